// Round 3
// baseline (618.785 us; speedup 1.0000x reference)
//
#include <hip/hip_runtime.h>

#define BB 2
#define NN 256
#define DD 512
#define HH 8

__device__ __forceinline__ float dot4(float4 a, float4 b) {
    return a.x*b.x + a.y*b.y + a.z*b.z + a.w*b.w;
}

__device__ __forceinline__ void gload_lds16(const void* g, void* l) {
    __builtin_amdgcn_global_load_lds(
        (const __attribute__((address_space(1))) unsigned int*)g,
        (__attribute__((address_space(3))) unsigned int*)l, 16, 0, 0);
}

// Stage 8 rows x 512 floats (16KB) global->LDS with per-row XOR swizzle.
// LDS slot (y,c) receives source element (y,c^y): dest linear, source
// per-lane pre-swizzled (m173 pattern).
__device__ __forceinline__ void stage_swz(const char* rowbase, float4* dst, int w, int lane) {
    #pragma unroll
    for (int j = 0; j < 4; ++j) {
        const int f0 = w * 256 + j * 64;
        const int y = f0 >> 7;
        const int c = (f0 & 127) + lane;
        gload_lds16(rowbase + (size_t)y * 2048 + ((size_t)(c ^ y) << 4), &dst[f0]);
    }
}

// ---------------- kProj: 3 linear layers ----------------
// grid 3072 = 3 proj x 64 rowgroups(8 rows) x 16 colslices(32 cols); block 256
__global__ __launch_bounds__(256) void kProj(
    const float* __restrict__ in_,
    const float* __restrict__ w0, const float* __restrict__ b0,
    const float* __restrict__ w1, const float* __restrict__ b1,
    const float* __restrict__ w2, const float* __restrict__ b2,
    float* __restrict__ o0, float* __restrict__ o1, float* __restrict__ o2)
{
    __shared__ float4 xs[8 * 128];   // 8 rows of input
    const int t = threadIdx.x;
    const int blk = blockIdx.x;
    const int proj = blk >> 10;
    const int rem = blk & 1023;
    const int rowg = rem >> 4;
    const int colsl = rem & 15;
    const int row0 = rowg * 8;

    const float* W; const float* Bp; float* O;
    if (proj == 0)      { W = w0; Bp = b0; O = o0; }
    else if (proj == 1) { W = w1; Bp = b1; O = o1; }
    else                { W = w2; Bp = b2; O = o2; }

    const float4* src = (const float4*)(in_ + (size_t)row0 * DD);
    #pragma unroll
    for (int j = 0; j < 4; ++j) xs[t + 256 * j] = src[t + 256 * j];
    __syncthreads();

    const int r = t >> 5;           // 0..7
    const int col = colsl * 32 + (t & 31);
    const float4* w4 = (const float4*)(W + (size_t)col * DD);
    const float4* xr4 = &xs[r * 128];
    float acc = 0.f;
    #pragma unroll 8
    for (int e4 = 0; e4 < 128; ++e4) acc += dot4(w4[e4], xr4[e4]);
    O[(size_t)(row0 + r) * DD + col] = acc + Bp[col];
}

// ---------------- kQkp: qkp[row,h,e] = sum_d q[row,h*64+d]*wrk[h*64+d,e] ----
// grid 2048 = 64 rowgroups(8 rows) x 8 h x 4 e-slices(128); block 256
__global__ __launch_bounds__(256) void kQkp(
    const float* __restrict__ q, const float* __restrict__ wrk,
    float* __restrict__ qkp)
{
    __shared__ float qs[8 * 64];
    const int t = threadIdx.x;
    const int blk = blockIdx.x;
    const int rowg = blk >> 5;
    const int h = (blk >> 2) & 7;
    const int eq = blk & 3;
    const int row0 = rowg * 8;
    {
        const int r = t >> 5, d2 = (t & 31) * 2;
        const float2 tmp = *(const float2*)(q + (size_t)(row0 + r) * DD + h * 64 + d2);
        qs[r * 64 + d2] = tmp.x; qs[r * 64 + d2 + 1] = tmp.y;
    }
    __syncthreads();
    const int e = eq * 128 + (t & 127);
    const int rp = (t >> 7) * 4;
    const float* wcol = wrk + (size_t)(h * 64) * DD + e;
    float a0 = 0, a1 = 0, a2 = 0, a3 = 0;
    #pragma unroll 8
    for (int d = 0; d < 64; ++d) {
        const float wv = wcol[(size_t)d * DD];
        a0 += qs[(rp + 0) * 64 + d] * wv;
        a1 += qs[(rp + 1) * 64 + d] * wv;
        a2 += qs[(rp + 2) * 64 + d] * wv;
        a3 += qs[(rp + 3) * 64 + d] * wv;
    }
    qkp[((size_t)(row0 + rp + 0) * HH + h) * DD + e] = a0;
    qkp[((size_t)(row0 + rp + 1) * HH + h) * DD + e] = a1;
    qkp[((size_t)(row0 + rp + 2) * HH + h) * DD + e] = a2;
    qkp[((size_t)(row0 + rp + 3) * HH + h) * DD + e] = a3;
}

// ---------------- kSk: sk[b,x,h,y] = 0.125*(q.k) + mask ----------------
// grid 2048 = 2b x 8h x 32 xt(8 rows) x 4 yt(64); block 256
__global__ __launch_bounds__(256) void kSk(
    const float* __restrict__ q, const float* __restrict__ k,
    const unsigned char* __restrict__ mask, float* __restrict__ sk)
{
    __shared__ float qs[8 * 65];
    __shared__ float ks[64 * 65];
    const int t = threadIdx.x;
    const int blk = blockIdx.x;
    const int b  = blk >> 10;
    const int h  = (blk >> 7) & 7;
    const int xt = (blk >> 2) & 31;
    const int yt = blk & 3;
    const int x0 = xt * 8, y0 = yt * 64;
    {
        const int r = t >> 5, d2 = (t & 31) * 2;
        const float2 tmp = *(const float2*)(q + (size_t)(b * NN + x0 + r) * DD + h * 64 + d2);
        qs[r * 65 + d2] = tmp.x; qs[r * 65 + d2 + 1] = tmp.y;
    }
    #pragma unroll
    for (int j = 0; j < 8; ++j) {
        const int f = t + 256 * j;
        const int r = f >> 5, d2 = (f & 31) * 2;
        const float2 tmp = *(const float2*)(k + (size_t)(b * NN + y0 + r) * DD + h * 64 + d2);
        ks[r * 65 + d2] = tmp.x; ks[r * 65 + d2 + 1] = tmp.y;
    }
    __syncthreads();
    const int xi = t >> 5, yg = t & 31;
    float a0 = 0, a1 = 0;
    #pragma unroll 8
    for (int d = 0; d < 64; ++d) {
        const float qv = qs[xi * 65 + d];
        a0 += qv * ks[(yg * 2 + 0) * 65 + d];
        a1 += qv * ks[(yg * 2 + 1) * 65 + d];
    }
    a0 *= 0.125f; a1 *= 0.125f;
    const unsigned char* mrow = mask + (size_t)(b * NN + x0 + xi) * NN;
    const int gy = y0 + yg * 2;
    if (mrow[gy + 0]) a0 = -1e9f;
    if (mrow[gy + 1]) a1 = -1e9f;
    float2 st; st.x = a0; st.y = a1;
    *(float2*)(sk + ((size_t)(b * NN + x0 + xi) * HH + h) * NN + gy) = st;
}

// ---------------- kC: flash attention over G, split-K 4 parts -------------
// grid 2048 = (b*N) x 4 parts; block 256; each block handles 64 y rows
__global__ __launch_bounds__(256) void kC(
    const float* __restrict__ G, const float* __restrict__ sk,
    const float* __restrict__ qkp, const float* __restrict__ v,
    float* __restrict__ pg, float* __restrict__ pxv,
    float* __restrict__ pm, float* __restrict__ pl)
{
    __shared__ float4 gbuf[2][1024];   // double-buffered 8x512 G tile, swizzled
    __shared__ float4 qk4[1024];       // qkp [8h][128], swizzled
    __shared__ float s_l[64];          // scores [8y][8h]

    const int t = threadIdx.x;
    const int lane = t & 63;
    const int w = t >> 6;
    const int blk = blockIdx.x;
    const int part = blk & 3;
    const int bid = blk >> 2;          // b*N + x
    const int b = bid >> 8;
    const int ybase = part * 64;

    const char* Grow = (const char*)(G + (size_t)bid * NN * DD);
    stage_swz((const char*)(qkp + (size_t)bid * HH * DD), qk4, w, lane);
    stage_swz(Grow + (size_t)ybase * 2048, &gbuf[0][0], w, lane);
    __syncthreads();

    const int s_  = t & 15;
    const int h0i = ((t >> 4) & 3) * 2;
    const int y0i = w * 2;
    const int ec4 = t & 127;
    const int hb  = (t >> 7) * 4;
    const int hv  = t >> 5;
    const int d2  = (t & 31) * 2;

    float4 gacc0 = {0,0,0,0}, gacc1 = {0,0,0,0}, gacc2 = {0,0,0,0}, gacc3 = {0,0,0,0};
    float m0 = -3e38f, m1 = -3e38f, m2 = -3e38f, m3 = -3e38f;
    float l0 = 0, l1 = 0, l2 = 0, l3 = 0;
    float vx = 0, vy = 0, mvold = -3e38f;

    const float* vrow = v + (size_t)(b * NN + ybase) * DD + hv * 64 + d2;
    const float* skrow = sk + (size_t)bid * HH * NN;

    int cb = 0;
    for (int tt = 0; tt < 8; ++tt) {
        if (tt < 7)
            stage_swz(Grow + (size_t)(ybase + (tt + 1) * 8) * 2048, &gbuf[cb ^ 1][0], w, lane);

        // ---- scores ----
        {
            float a00 = 0, a01 = 0, a10 = 0, a11 = 0;
            const float4* gb = &gbuf[cb][0];
            #pragma unroll
            for (int i = 0; i < 8; ++i) {
                const int e4 = i * 16 + s_;
                const float4 g0 = gb[y0i * 128 + (e4 ^ y0i)];
                const float4 g1 = gb[(y0i + 1) * 128 + (e4 ^ (y0i + 1))];
                const float4 p0 = qk4[h0i * 128 + (e4 ^ h0i)];
                const float4 p1 = qk4[(h0i + 1) * 128 + (e4 ^ (h0i + 1))];
                a00 += dot4(g0, p0); a01 += dot4(g0, p1);
                a10 += dot4(g1, p0); a11 += dot4(g1, p1);
            }
            #pragma unroll
            for (int mm = 1; mm < 16; mm <<= 1) {
                a00 += __shfl_xor(a00, mm); a01 += __shfl_xor(a01, mm);
                a10 += __shfl_xor(a10, mm); a11 += __shfl_xor(a11, mm);
            }
            if (s_ < 4) {
                const int yy = s_ & 1, hh = s_ >> 1;
                const float val = yy ? (hh ? a11 : a10) : (hh ? a01 : a00);
                const int gy = ybase + tt * 8 + y0i + yy;
                const int h = h0i + hh;
                s_l[(y0i + yy) * 8 + h] = val * 0.125f + skrow[(size_t)h * NN + gy];
            }
        }
        __syncthreads();

        // ---- per-thread softmax update + accumulate ----
        {
            {   const float tmx0 = fmaxf(fmaxf(fmaxf(s_l[0*8+hb+0], s_l[1*8+hb+0]), fmaxf(s_l[2*8+hb+0], s_l[3*8+hb+0])),
                                         fmaxf(fmaxf(s_l[4*8+hb+0], s_l[5*8+hb+0]), fmaxf(s_l[6*8+hb+0], s_l[7*8+hb+0])));
                const float mn = fmaxf(m0, tmx0); const float rs = __expf(m0 - mn);
                m0 = mn; l0 *= rs; gacc0.x *= rs; gacc0.y *= rs; gacc0.z *= rs; gacc0.w *= rs; }
            {   const float tmx1 = fmaxf(fmaxf(fmaxf(s_l[0*8+hb+1], s_l[1*8+hb+1]), fmaxf(s_l[2*8+hb+1], s_l[3*8+hb+1])),
                                         fmaxf(fmaxf(s_l[4*8+hb+1], s_l[5*8+hb+1]), fmaxf(s_l[6*8+hb+1], s_l[7*8+hb+1])));
                const float mn = fmaxf(m1, tmx1); const float rs = __expf(m1 - mn);
                m1 = mn; l1 *= rs; gacc1.x *= rs; gacc1.y *= rs; gacc1.z *= rs; gacc1.w *= rs; }
            {   const float tmx2 = fmaxf(fmaxf(fmaxf(s_l[0*8+hb+2], s_l[1*8+hb+2]), fmaxf(s_l[2*8+hb+2], s_l[3*8+hb+2])),
                                         fmaxf(fmaxf(s_l[4*8+hb+2], s_l[5*8+hb+2]), fmaxf(s_l[6*8+hb+2], s_l[7*8+hb+2])));
                const float mn = fmaxf(m2, tmx2); const float rs = __expf(m2 - mn);
                m2 = mn; l2 *= rs; gacc2.x *= rs; gacc2.y *= rs; gacc2.z *= rs; gacc2.w *= rs; }
            {   const float tmx3 = fmaxf(fmaxf(fmaxf(s_l[0*8+hb+3], s_l[1*8+hb+3]), fmaxf(s_l[2*8+hb+3], s_l[3*8+hb+3])),
                                         fmaxf(fmaxf(s_l[4*8+hb+3], s_l[5*8+hb+3]), fmaxf(s_l[6*8+hb+3], s_l[7*8+hb+3])));
                const float mn = fmaxf(m3, tmx3); const float rs = __expf(m3 - mn);
                m3 = mn; l3 *= rs; gacc3.x *= rs; gacc3.y *= rs; gacc3.z *= rs; gacc3.w *= rs; }

            const int ri = hv & 3;
            const float mv = (ri & 2) ? ((ri & 1) ? m3 : m2) : ((ri & 1) ? m1 : m0);
            const float rv = __expf(mvold - mv);
            vx *= rv; vy *= rv; mvold = mv;

            const float4* gb = &gbuf[cb][0];
            const float* vt = vrow + (size_t)tt * 8 * DD;
            #pragma unroll
            for (int y = 0; y < 8; ++y) {
                const float4 gv = gb[y * 128 + (ec4 ^ y)];
                const float2 vv = *(const float2*)(vt + (size_t)y * DD);
                const float p0 = __expf(s_l[y*8 + hb + 0] - m0); l0 += p0;
                gacc0.x += p0*gv.x; gacc0.y += p0*gv.y; gacc0.z += p0*gv.z; gacc0.w += p0*gv.w;
                const float p1 = __expf(s_l[y*8 + hb + 1] - m1); l1 += p1;
                gacc1.x += p1*gv.x; gacc1.y += p1*gv.y; gacc1.z += p1*gv.z; gacc1.w += p1*gv.w;
                const float p2 = __expf(s_l[y*8 + hb + 2] - m2); l2 += p2;
                gacc2.x += p2*gv.x; gacc2.y += p2*gv.y; gacc2.z += p2*gv.z; gacc2.w += p2*gv.w;
                const float p3 = __expf(s_l[y*8 + hb + 3] - m3); l3 += p3;
                gacc3.x += p3*gv.x; gacc3.y += p3*gv.y; gacc3.z += p3*gv.z; gacc3.w += p3*gv.w;
                const float pv = __expf(s_l[y*8 + hv] - mv);
                vx += pv * vv.x; vy += pv * vv.y;
            }
        }
        __syncthreads();
        cb ^= 1;
    }

    float4* pgb = (float4*)pg + (size_t)blk * 1024;
    pgb[(hb + 0) * 128 + ec4] = gacc0;
    pgb[(hb + 1) * 128 + ec4] = gacc1;
    pgb[(hb + 2) * 128 + ec4] = gacc2;
    pgb[(hb + 3) * 128 + ec4] = gacc3;
    float2 xvst; xvst.x = vx; xvst.y = vy;
    *(float2*)(pxv + (size_t)blk * DD + hv * 64 + d2) = xvst;
    if ((t & 127) == 0) {
        const int base = blk * 8 + hb;
        pm[base + 0] = m0; pm[base + 1] = m1; pm[base + 2] = m2; pm[base + 3] = m3;
        pl[base + 0] = l0; pl[base + 1] = l1; pl[base + 2] = l2; pl[base + 3] = l3;
    }
}

// ---------------- kM: merge 4 partials + wrv GEMV epilogue ----------------
// grid 1024 = bid x 2 output-halves (h 0-3 / 4-7); block 256
__global__ __launch_bounds__(256) void kM(
    const float* __restrict__ pg, const float* __restrict__ pxv,
    const float* __restrict__ pm, const float* __restrict__ pl,
    const float* __restrict__ wrv, const float* __restrict__ brv,
    float* __restrict__ om)
{
    __shared__ float4 gc[512];      // combined g_agg [4h][128]
    __shared__ float xvs[256];
    __shared__ float wexp[16], Ls[4];
    const int t = threadIdx.x;
    const int blk = blockIdx.x;
    const int bid = blk >> 1;
    const int half = blk & 1;
    const int h0 = half * 4;
    __shared__ float mlds[16], llds[16];
    if (t < 16) {
        const int i = t >> 2, hh = t & 3;
        mlds[t] = pm[bid * 32 + i * 8 + h0 + hh];
        llds[t] = pl[bid * 32 + i * 8 + h0 + hh];
    }
    __syncthreads();
    if (t < 4) {
        float M = mlds[t];
        #pragma unroll
        for (int i = 1; i < 4; ++i) M = fmaxf(M, mlds[i * 4 + t]);
        float L = 0;
        #pragma unroll
        for (int i = 0; i < 4; ++i) {
            const float wv = __expf(mlds[i * 4 + t] - M);
            wexp[i * 4 + t] = wv;
            L += wv * llds[i * 4 + t];
        }
        Ls[t] = L;
    }
    __syncthreads();
    const int c4 = t & 127;
    #pragma unroll
    for (int r = 0; r < 2; ++r) {
        const int hh = (t >> 7) * 2 + r;       // 0..3 local
        float4 acc = {0, 0, 0, 0};
        #pragma unroll
        for (int i = 0; i < 4; ++i) {
            const float wv = wexp[i * 4 + hh];
            const float4 g = ((const float4*)pg)[((size_t)bid * 4 + i) * 1024 + (size_t)(h0 + hh) * 128 + c4];
            acc.x += wv * g.x; acc.y += wv * g.y; acc.z += wv * g.z; acc.w += wv * g.w;
        }
        gc[hh * 128 + c4] = acc;
    }
    {
        const int hh = t >> 6;                 // 0..3 local
        float s = 0;
        #pragma unroll
        for (int i = 0; i < 4; ++i)
            s += wexp[i * 4 + hh] * pxv[((size_t)bid * 4 + i) * DD + half * 256 + t];
        xvs[t] = s;
    }
    __syncthreads();
    const int o = half * 256 + t;
    const int hl = t >> 6;                     // 0..3 local
    const float4* wr4 = (const float4*)(wrv + (size_t)o * DD);
    float acc = 0;
    #pragma unroll 4
    for (int e4 = 0; e4 < 128; ++e4) acc += dot4(wr4[e4], gc[hl * 128 + e4]);
    om[(size_t)bid * DD + o] = (xvs[t] + acc) / Ls[hl] + brv[o];
}

// ---------------- kE: new_graphs = xl[:,:,None,:] + xr[:,None,:,:] -------
// grid 2048 = 512 bid x 4 y-chunks; block 256
__global__ __launch_bounds__(256) void kE(
    const float* __restrict__ xl, const float* __restrict__ xr,
    float* __restrict__ ng)
{
    const int t = threadIdx.x;
    const int blk = blockIdx.x;
    const int bid = blk >> 2;
    const int yc = blk & 3;
    const int b = bid >> 8;
    const int o4 = t & 127;
    const int yh = t >> 7;
    const float4 left = ((const float4*)xl)[(size_t)bid * 128 + o4];
    const float4* xr4 = (const float4*)xr + (size_t)b * NN * 128;
    float4* out4 = (float4*)ng + (size_t)bid * NN * 128;
    for (int y = yc * 64 + yh; y < yc * 64 + 64; y += 2) {
        const float4 rr = xr4[y * 128 + o4];
        float4 s;
        s.x = left.x + rr.x; s.y = left.y + rr.y;
        s.z = left.z + rr.z; s.w = left.w + rr.w;
        out4[y * 128 + o4] = s;
    }
}

extern "C" void kernel_launch(void* const* d_in, const int* in_sizes, int n_in,
                              void* d_out, int out_size, void* d_ws, size_t ws_size,
                              hipStream_t stream)
{
    (void)in_sizes; (void)n_in; (void)out_size; (void)ws_size;
    const float* x    = (const float*)d_in[0];
    const float* G    = (const float*)d_in[1];
    const unsigned char* mask = (const unsigned char*)d_in[2];
    const float* wq  = (const float*)d_in[3];  const float* bq  = (const float*)d_in[4];
    const float* wk  = (const float*)d_in[5];  const float* bk  = (const float*)d_in[6];
    const float* wv  = (const float*)d_in[7];  const float* bv  = (const float*)d_in[8];
    const float* wo  = (const float*)d_in[9];  const float* bo  = (const float*)d_in[10];
    const float* wl  = (const float*)d_in[11]; const float* bl  = (const float*)d_in[12];
    const float* wr  = (const float*)d_in[13]; const float* br  = (const float*)d_in[14];
    const float* wrk = (const float*)d_in[15]; /* brk unused: softmax-invariant */
    const float* wrv = (const float*)d_in[17]; const float* brv = (const float*)d_in[18];

    float* out  = (float*)d_out;
    float* fout = out;                          // [B,N,D]
    float* ng   = out + (size_t)BB * NN * DD;   // [B,N,N,D]

    // Scratch in the tail of the ng region: all consumed before kE overwrites.
    const size_t ng_f  = (size_t)BB * NN * NN * DD;   // 67,108,864
    const size_t row_f = (size_t)BB * NN * DD;        // 262,144
    const size_t total = row_f * 52 + 32768;
    float* base = ng + ng_f - total;
    float* q    = base;
    float* k    = q   + row_f;
    float* vv_  = k   + row_f;
    float* qkp  = vv_ + row_f;          // row_f * 8
    float* skp  = qkp + row_f * 8;      // row_f * 4
    float* pg   = skp + row_f * 4;      // row_f * 32
    float* pxv  = pg  + row_f * 32;     // row_f * 4
    float* pm   = pxv + row_f * 4;      // 16384
    float* pl   = pm  + 16384;          // 16384
    float* om   = pl  + 16384;          // row_f
    float* xl = (float*)d_ws;           // survives into kE -> d_ws
    float* xr = xl + row_f;

    kProj<<<3072, 256, 0, stream>>>(x, wq, bq, wk, bk, wv, bv, q, k, vv_);
    kQkp <<<2048, 256, 0, stream>>>(q, wrk, qkp);
    kSk  <<<2048, 256, 0, stream>>>(q, k, mask, skp);
    kC   <<<2048, 256, 0, stream>>>(G, skp, qkp, vv_, pg, pxv, pm, pl);
    kM   <<<1024, 256, 0, stream>>>(pg, pxv, pm, pl, wrv, brv, om);
    kProj<<<3072, 256, 0, stream>>>(om, wo, bo, wl, bl, wr, br, fout, xl, xr);
    kE   <<<2048, 256, 0, stream>>>(xl, xr, ng);
}

// Round 4
// 301.628 us; speedup vs baseline: 2.0515x; 2.0515x over previous
//
#include <hip/hip_runtime.h>

#define BB 2
#define NN 256
#define DD 512
#define HH 8

__device__ __forceinline__ float dot4(float4 a, float4 b) {
    return a.x*b.x + a.y*b.y + a.z*b.z + a.w*b.w;
}

__device__ __forceinline__ void gload_lds16(const void* g, void* l) {
    __builtin_amdgcn_global_load_lds(
        (const __attribute__((address_space(1))) unsigned int*)g,
        (__attribute__((address_space(3))) unsigned int*)l, 16, 0, 0);
}

// Stage 8 rows x 512 floats (16KB) global->LDS with per-row XOR swizzle.
// LDS slot (y,c) receives source element (y,c^y): dest linear, source
// per-lane pre-swizzled (m173 pattern).
__device__ __forceinline__ void stage_swz(const char* rowbase, float4* dst, int w, int lane) {
    #pragma unroll
    for (int j = 0; j < 4; ++j) {
        const int f0 = w * 256 + j * 64;
        const int y = f0 >> 7;
        const int c = (f0 & 127) + lane;
        gload_lds16(rowbase + (size_t)y * 2048 + ((size_t)(c ^ y) << 4), &dst[f0]);
    }
}

// ---------------- kProj: 3 linear layers as tiled GEMM --------------------
// O = X @ W^T + b. grid 768 = 3 proj x 16 rowtiles x 16 coltiles (32x32 tile)
// block 256; K-chunk 64, double-buffered LDS, 2x2 micro-tile.
__global__ __launch_bounds__(256) void kProj(
    const float* __restrict__ in_,
    const float* __restrict__ w0, const float* __restrict__ b0,
    const float* __restrict__ w1, const float* __restrict__ b1,
    const float* __restrict__ w2, const float* __restrict__ b2,
    float* __restrict__ o0, float* __restrict__ o1, float* __restrict__ o2)
{
    __shared__ float4 xs[2][32 * 17];   // 32 rows x 16 float4 (+1 pad)
    __shared__ float4 ws[2][32 * 17];

    const int t = threadIdx.x;
    const int blk = blockIdx.x;
    const int proj = blk >> 8;
    const int rem = blk & 255;
    const int row0 = (rem >> 4) * 32;
    const int col0 = (rem & 15) * 32;

    const float* W; const float* Bp; float* O;
    if (proj == 0)      { W = w0; Bp = b0; O = o0; }
    else if (proj == 1) { W = w1; Bp = b1; O = o1; }
    else                { W = w2; Bp = b2; O = o2; }

    // staging map: f in {t, t+256}; row = f>>4 (0..31), e4 = f&15
    const int sr0 = t >> 4,          se0 = t & 15;
    const int sr1 = (t + 256) >> 4,  se1 = t & 15;   // (t+256)&15 == t&15
    const float4* X4 = (const float4*)in_;
    const float4* W4 = (const float4*)W;

    // prefetch chunk 0
    float4 rx0 = X4[(size_t)(row0 + sr0) * 128 + se0];
    float4 rx1 = X4[(size_t)(row0 + sr1) * 128 + se1];
    float4 rw0 = W4[(size_t)(col0 + sr0) * 128 + se0];
    float4 rw1 = W4[(size_t)(col0 + sr1) * 128 + se1];
    xs[0][sr0 * 17 + se0] = rx0;
    xs[0][sr1 * 17 + se1] = rx1;
    ws[0][sr0 * 17 + se0] = rw0;
    ws[0][sr1 * 17 + se1] = rw1;

    const int ty = t >> 4, tx = t & 15;
    const int ra = 2 * ty, ca = 2 * tx;
    float a00 = 0, a01 = 0, a10 = 0, a11 = 0;

    for (int q = 0; q < 8; ++q) {
        __syncthreads();
        const int cur = q & 1;
        if (q < 7) {
            const int koff = (q + 1) * 16;
            rx0 = X4[(size_t)(row0 + sr0) * 128 + koff + se0];
            rx1 = X4[(size_t)(row0 + sr1) * 128 + koff + se1];
            rw0 = W4[(size_t)(col0 + sr0) * 128 + koff + se0];
            rw1 = W4[(size_t)(col0 + sr1) * 128 + koff + se1];
        }
        const float4* xb = xs[cur];
        const float4* wb = ws[cur];
        #pragma unroll
        for (int e4 = 0; e4 < 16; ++e4) {
            const float4 x0 = xb[ra * 17 + e4];
            const float4 x1 = xb[(ra + 1) * 17 + e4];
            const float4 v0 = wb[ca * 17 + e4];
            const float4 v1 = wb[(ca + 1) * 17 + e4];
            a00 += dot4(x0, v0); a01 += dot4(x0, v1);
            a10 += dot4(x1, v0); a11 += dot4(x1, v1);
        }
        if (q < 7) {
            const int nxt = cur ^ 1;
            xs[nxt][sr0 * 17 + se0] = rx0;
            xs[nxt][sr1 * 17 + se1] = rx1;
            ws[nxt][sr0 * 17 + se0] = rw0;
            ws[nxt][sr1 * 17 + se1] = rw1;
        }
    }

    const int orow = row0 + ra, ocol = col0 + ca;
    const float bx = Bp[ocol], by = Bp[ocol + 1];
    float2 s0; s0.x = a00 + bx; s0.y = a01 + by;
    float2 s1; s1.x = a10 + bx; s1.y = a11 + by;
    *(float2*)(O + (size_t)orow * DD + ocol) = s0;
    *(float2*)(O + (size_t)(orow + 1) * DD + ocol) = s1;
}

// ---------------- kQkp: qkp[row,h,e] = sum_d q[row,h*64+d]*wrk[h*64+d,e] ----
// grid 2048 = 64 rowgroups(8 rows) x 8 h x 4 e-slices(128); block 256
__global__ __launch_bounds__(256) void kQkp(
    const float* __restrict__ q, const float* __restrict__ wrk,
    float* __restrict__ qkp)
{
    __shared__ float qs[8 * 64];
    const int t = threadIdx.x;
    const int blk = blockIdx.x;
    const int rowg = blk >> 5;
    const int h = (blk >> 2) & 7;
    const int eq = blk & 3;
    const int row0 = rowg * 8;
    {
        const int r = t >> 5, d2 = (t & 31) * 2;
        const float2 tmp = *(const float2*)(q + (size_t)(row0 + r) * DD + h * 64 + d2);
        qs[r * 64 + d2] = tmp.x; qs[r * 64 + d2 + 1] = tmp.y;
    }
    __syncthreads();
    const int e = eq * 128 + (t & 127);
    const int rp = (t >> 7) * 4;
    const float* wcol = wrk + (size_t)(h * 64) * DD + e;
    float a0 = 0, a1 = 0, a2 = 0, a3 = 0;
    #pragma unroll 8
    for (int d = 0; d < 64; ++d) {
        const float wv = wcol[(size_t)d * DD];
        a0 += qs[(rp + 0) * 64 + d] * wv;
        a1 += qs[(rp + 1) * 64 + d] * wv;
        a2 += qs[(rp + 2) * 64 + d] * wv;
        a3 += qs[(rp + 3) * 64 + d] * wv;
    }
    qkp[((size_t)(row0 + rp + 0) * HH + h) * DD + e] = a0;
    qkp[((size_t)(row0 + rp + 1) * HH + h) * DD + e] = a1;
    qkp[((size_t)(row0 + rp + 2) * HH + h) * DD + e] = a2;
    qkp[((size_t)(row0 + rp + 3) * HH + h) * DD + e] = a3;
}

// ---------------- kSk: sk[b,x,h,y] = 0.125*(q.k) + mask ----------------
// grid 2048 = 2b x 8h x 32 xt(8 rows) x 4 yt(64); block 256
__global__ __launch_bounds__(256) void kSk(
    const float* __restrict__ q, const float* __restrict__ k,
    const unsigned char* __restrict__ mask, float* __restrict__ sk)
{
    __shared__ float qs[8 * 65];
    __shared__ float ks[64 * 65];
    const int t = threadIdx.x;
    const int blk = blockIdx.x;
    const int b  = blk >> 10;
    const int h  = (blk >> 7) & 7;
    const int xt = (blk >> 2) & 31;
    const int yt = blk & 3;
    const int x0 = xt * 8, y0 = yt * 64;
    {
        const int r = t >> 5, d2 = (t & 31) * 2;
        const float2 tmp = *(const float2*)(q + (size_t)(b * NN + x0 + r) * DD + h * 64 + d2);
        qs[r * 65 + d2] = tmp.x; qs[r * 65 + d2 + 1] = tmp.y;
    }
    #pragma unroll
    for (int j = 0; j < 8; ++j) {
        const int f = t + 256 * j;
        const int r = f >> 5, d2 = (f & 31) * 2;
        const float2 tmp = *(const float2*)(k + (size_t)(b * NN + y0 + r) * DD + h * 64 + d2);
        ks[r * 65 + d2] = tmp.x; ks[r * 65 + d2 + 1] = tmp.y;
    }
    __syncthreads();
    const int xi = t >> 5, yg = t & 31;
    float a0 = 0, a1 = 0;
    #pragma unroll 8
    for (int d = 0; d < 64; ++d) {
        const float qv = qs[xi * 65 + d];
        a0 += qv * ks[(yg * 2 + 0) * 65 + d];
        a1 += qv * ks[(yg * 2 + 1) * 65 + d];
    }
    a0 *= 0.125f; a1 *= 0.125f;
    const unsigned char* mrow = mask + (size_t)(b * NN + x0 + xi) * NN;
    const int gy = y0 + yg * 2;
    if (mrow[gy + 0]) a0 = -1e9f;
    if (mrow[gy + 1]) a1 = -1e9f;
    float2 st; st.x = a0; st.y = a1;
    *(float2*)(sk + ((size_t)(b * NN + x0 + xi) * HH + h) * NN + gy) = st;
}

// ---------------- kC: flash attention over G, split-K 4 parts -------------
// grid 2048 = (b*N) x 4 parts; block 256; each block handles 64 y rows
__global__ __launch_bounds__(256) void kC(
    const float* __restrict__ G, const float* __restrict__ sk,
    const float* __restrict__ qkp, const float* __restrict__ v,
    float* __restrict__ pg, float* __restrict__ pxv,
    float* __restrict__ pm, float* __restrict__ pl)
{
    __shared__ float4 gbuf[2][1024];   // double-buffered 8x512 G tile, swizzled
    __shared__ float4 qk4[1024];       // qkp [8h][128], swizzled
    __shared__ float s_l[64];          // scores [8y][8h]

    const int t = threadIdx.x;
    const int lane = t & 63;
    const int w = t >> 6;
    const int blk = blockIdx.x;
    const int part = blk & 3;
    const int bid = blk >> 2;          // b*N + x
    const int b = bid >> 8;
    const int ybase = part * 64;

    const char* Grow = (const char*)(G + (size_t)bid * NN * DD);
    stage_swz((const char*)(qkp + (size_t)bid * HH * DD), qk4, w, lane);
    stage_swz(Grow + (size_t)ybase * 2048, &gbuf[0][0], w, lane);
    __syncthreads();

    const int s_  = t & 15;
    const int h0i = ((t >> 4) & 3) * 2;
    const int y0i = w * 2;
    const int ec4 = t & 127;
    const int hb  = (t >> 7) * 4;
    const int hv  = t >> 5;
    const int d2  = (t & 31) * 2;

    float4 gacc0 = {0,0,0,0}, gacc1 = {0,0,0,0}, gacc2 = {0,0,0,0}, gacc3 = {0,0,0,0};
    float m0 = -3e38f, m1 = -3e38f, m2 = -3e38f, m3 = -3e38f;
    float l0 = 0, l1 = 0, l2 = 0, l3 = 0;
    float vx = 0, vy = 0, mvold = -3e38f;

    const float* vrow = v + (size_t)(b * NN + ybase) * DD + hv * 64 + d2;
    const float* skrow = sk + (size_t)bid * HH * NN;

    int cb = 0;
    for (int tt = 0; tt < 8; ++tt) {
        if (tt < 7)
            stage_swz(Grow + (size_t)(ybase + (tt + 1) * 8) * 2048, &gbuf[cb ^ 1][0], w, lane);

        // ---- scores ----
        {
            float a00 = 0, a01 = 0, a10 = 0, a11 = 0;
            const float4* gb = &gbuf[cb][0];
            #pragma unroll
            for (int i = 0; i < 8; ++i) {
                const int e4 = i * 16 + s_;
                const float4 g0 = gb[y0i * 128 + (e4 ^ y0i)];
                const float4 g1 = gb[(y0i + 1) * 128 + (e4 ^ (y0i + 1))];
                const float4 p0 = qk4[h0i * 128 + (e4 ^ h0i)];
                const float4 p1 = qk4[(h0i + 1) * 128 + (e4 ^ (h0i + 1))];
                a00 += dot4(g0, p0); a01 += dot4(g0, p1);
                a10 += dot4(g1, p0); a11 += dot4(g1, p1);
            }
            #pragma unroll
            for (int mm = 1; mm < 16; mm <<= 1) {
                a00 += __shfl_xor(a00, mm); a01 += __shfl_xor(a01, mm);
                a10 += __shfl_xor(a10, mm); a11 += __shfl_xor(a11, mm);
            }
            if (s_ < 4) {
                const int yy = s_ & 1, hh = s_ >> 1;
                const float val = yy ? (hh ? a11 : a10) : (hh ? a01 : a00);
                const int gy = ybase + tt * 8 + y0i + yy;
                const int h = h0i + hh;
                s_l[(y0i + yy) * 8 + h] = val * 0.125f + skrow[(size_t)h * NN + gy];
            }
        }
        __syncthreads();

        // ---- per-thread softmax update + accumulate ----
        {
            {   const float tmx0 = fmaxf(fmaxf(fmaxf(s_l[0*8+hb+0], s_l[1*8+hb+0]), fmaxf(s_l[2*8+hb+0], s_l[3*8+hb+0])),
                                         fmaxf(fmaxf(s_l[4*8+hb+0], s_l[5*8+hb+0]), fmaxf(s_l[6*8+hb+0], s_l[7*8+hb+0])));
                const float mn = fmaxf(m0, tmx0); const float rs = __expf(m0 - mn);
                m0 = mn; l0 *= rs; gacc0.x *= rs; gacc0.y *= rs; gacc0.z *= rs; gacc0.w *= rs; }
            {   const float tmx1 = fmaxf(fmaxf(fmaxf(s_l[0*8+hb+1], s_l[1*8+hb+1]), fmaxf(s_l[2*8+hb+1], s_l[3*8+hb+1])),
                                         fmaxf(fmaxf(s_l[4*8+hb+1], s_l[5*8+hb+1]), fmaxf(s_l[6*8+hb+1], s_l[7*8+hb+1])));
                const float mn = fmaxf(m1, tmx1); const float rs = __expf(m1 - mn);
                m1 = mn; l1 *= rs; gacc1.x *= rs; gacc1.y *= rs; gacc1.z *= rs; gacc1.w *= rs; }
            {   const float tmx2 = fmaxf(fmaxf(fmaxf(s_l[0*8+hb+2], s_l[1*8+hb+2]), fmaxf(s_l[2*8+hb+2], s_l[3*8+hb+2])),
                                         fmaxf(fmaxf(s_l[4*8+hb+2], s_l[5*8+hb+2]), fmaxf(s_l[6*8+hb+2], s_l[7*8+hb+2])));
                const float mn = fmaxf(m2, tmx2); const float rs = __expf(m2 - mn);
                m2 = mn; l2 *= rs; gacc2.x *= rs; gacc2.y *= rs; gacc2.z *= rs; gacc2.w *= rs; }
            {   const float tmx3 = fmaxf(fmaxf(fmaxf(s_l[0*8+hb+3], s_l[1*8+hb+3]), fmaxf(s_l[2*8+hb+3], s_l[3*8+hb+3])),
                                         fmaxf(fmaxf(s_l[4*8+hb+3], s_l[5*8+hb+3]), fmaxf(s_l[6*8+hb+3], s_l[7*8+hb+3])));
                const float mn = fmaxf(m3, tmx3); const float rs = __expf(m3 - mn);
                m3 = mn; l3 *= rs; gacc3.x *= rs; gacc3.y *= rs; gacc3.z *= rs; gacc3.w *= rs; }

            const int ri = hv & 3;
            const float mv = (ri & 2) ? ((ri & 1) ? m3 : m2) : ((ri & 1) ? m1 : m0);
            const float rv = __expf(mvold - mv);
            vx *= rv; vy *= rv; mvold = mv;

            const float4* gb = &gbuf[cb][0];
            const float* vt = vrow + (size_t)tt * 8 * DD;
            #pragma unroll
            for (int y = 0; y < 8; ++y) {
                const float4 gv = gb[y * 128 + (ec4 ^ y)];
                const float2 vv = *(const float2*)(vt + (size_t)y * DD);
                const float p0 = __expf(s_l[y*8 + hb + 0] - m0); l0 += p0;
                gacc0.x += p0*gv.x; gacc0.y += p0*gv.y; gacc0.z += p0*gv.z; gacc0.w += p0*gv.w;
                const float p1 = __expf(s_l[y*8 + hb + 1] - m1); l1 += p1;
                gacc1.x += p1*gv.x; gacc1.y += p1*gv.y; gacc1.z += p1*gv.z; gacc1.w += p1*gv.w;
                const float p2 = __expf(s_l[y*8 + hb + 2] - m2); l2 += p2;
                gacc2.x += p2*gv.x; gacc2.y += p2*gv.y; gacc2.z += p2*gv.z; gacc2.w += p2*gv.w;
                const float p3 = __expf(s_l[y*8 + hb + 3] - m3); l3 += p3;
                gacc3.x += p3*gv.x; gacc3.y += p3*gv.y; gacc3.z += p3*gv.z; gacc3.w += p3*gv.w;
                const float pv = __expf(s_l[y*8 + hv] - mv);
                vx += pv * vv.x; vy += pv * vv.y;
            }
        }
        __syncthreads();
        cb ^= 1;
    }

    float4* pgb = (float4*)pg + (size_t)blk * 1024;
    pgb[(hb + 0) * 128 + ec4] = gacc0;
    pgb[(hb + 1) * 128 + ec4] = gacc1;
    pgb[(hb + 2) * 128 + ec4] = gacc2;
    pgb[(hb + 3) * 128 + ec4] = gacc3;
    float2 xvst; xvst.x = vx; xvst.y = vy;
    *(float2*)(pxv + (size_t)blk * DD + hv * 64 + d2) = xvst;
    if ((t & 127) == 0) {
        const int base = blk * 8 + hb;
        pm[base + 0] = m0; pm[base + 1] = m1; pm[base + 2] = m2; pm[base + 3] = m3;
        pl[base + 0] = l0; pl[base + 1] = l1; pl[base + 2] = l2; pl[base + 3] = l3;
    }
}

// ---------------- kM: merge 4 partials + wrv GEMV epilogue ----------------
// grid 1024 = bid x 2 output-halves (h 0-3 / 4-7); block 256
__global__ __launch_bounds__(256) void kM(
    const float* __restrict__ pg, const float* __restrict__ pxv,
    const float* __restrict__ pm, const float* __restrict__ pl,
    const float* __restrict__ wrv, const float* __restrict__ brv,
    float* __restrict__ om)
{
    __shared__ float4 gc[512];      // combined g_agg [4h][128]
    __shared__ float xvs[256];
    __shared__ float wexp[16], Ls[4];
    const int t = threadIdx.x;
    const int blk = blockIdx.x;
    const int bid = blk >> 1;
    const int half = blk & 1;
    const int h0 = half * 4;
    __shared__ float mlds[16], llds[16];
    if (t < 16) {
        const int i = t >> 2, hh = t & 3;
        mlds[t] = pm[bid * 32 + i * 8 + h0 + hh];
        llds[t] = pl[bid * 32 + i * 8 + h0 + hh];
    }
    __syncthreads();
    if (t < 4) {
        float M = mlds[t];
        #pragma unroll
        for (int i = 1; i < 4; ++i) M = fmaxf(M, mlds[i * 4 + t]);
        float L = 0;
        #pragma unroll
        for (int i = 0; i < 4; ++i) {
            const float wv = __expf(mlds[i * 4 + t] - M);
            wexp[i * 4 + t] = wv;
            L += wv * llds[i * 4 + t];
        }
        Ls[t] = L;
    }
    __syncthreads();
    const int c4 = t & 127;
    #pragma unroll
    for (int r = 0; r < 2; ++r) {
        const int hh = (t >> 7) * 2 + r;       // 0..3 local
        float4 acc = {0, 0, 0, 0};
        #pragma unroll
        for (int i = 0; i < 4; ++i) {
            const float wv = wexp[i * 4 + hh];
            const float4 g = ((const float4*)pg)[((size_t)bid * 4 + i) * 1024 + (size_t)(h0 + hh) * 128 + c4];
            acc.x += wv * g.x; acc.y += wv * g.y; acc.z += wv * g.z; acc.w += wv * g.w;
        }
        gc[hh * 128 + c4] = acc;
    }
    {
        const int hh = t >> 6;                 // 0..3 local
        float s = 0;
        #pragma unroll
        for (int i = 0; i < 4; ++i)
            s += wexp[i * 4 + hh] * pxv[((size_t)bid * 4 + i) * DD + half * 256 + t];
        xvs[t] = s;
    }
    __syncthreads();
    const int o = half * 256 + t;
    const int hl = t >> 6;                     // 0..3 local
    const float4* wr4 = (const float4*)(wrv + (size_t)o * DD);
    float acc = 0;
    #pragma unroll 4
    for (int e4 = 0; e4 < 128; ++e4) acc += dot4(wr4[e4], gc[hl * 128 + e4]);
    om[(size_t)bid * DD + o] = (xvs[t] + acc) / Ls[hl] + brv[o];
}

// ---------------- kE: new_graphs = xl[:,:,None,:] + xr[:,None,:,:] -------
// grid 2048 = 512 bid x 4 y-chunks; block 256
__global__ __launch_bounds__(256) void kE(
    const float* __restrict__ xl, const float* __restrict__ xr,
    float* __restrict__ ng)
{
    const int t = threadIdx.x;
    const int blk = blockIdx.x;
    const int bid = blk >> 2;
    const int yc = blk & 3;
    const int b = bid >> 8;
    const int o4 = t & 127;
    const int yh = t >> 7;
    const float4 left = ((const float4*)xl)[(size_t)bid * 128 + o4];
    const float4* xr4 = (const float4*)xr + (size_t)b * NN * 128;
    float4* out4 = (float4*)ng + (size_t)bid * NN * 128;
    for (int y = yc * 64 + yh; y < yc * 64 + 64; y += 2) {
        const float4 rr = xr4[y * 128 + o4];
        float4 s;
        s.x = left.x + rr.x; s.y = left.y + rr.y;
        s.z = left.z + rr.z; s.w = left.w + rr.w;
        out4[y * 128 + o4] = s;
    }
}

extern "C" void kernel_launch(void* const* d_in, const int* in_sizes, int n_in,
                              void* d_out, int out_size, void* d_ws, size_t ws_size,
                              hipStream_t stream)
{
    (void)in_sizes; (void)n_in; (void)out_size; (void)ws_size;
    const float* x    = (const float*)d_in[0];
    const float* G    = (const float*)d_in[1];
    const unsigned char* mask = (const unsigned char*)d_in[2];
    const float* wq  = (const float*)d_in[3];  const float* bq  = (const float*)d_in[4];
    const float* wk  = (const float*)d_in[5];  const float* bk  = (const float*)d_in[6];
    const float* wv  = (const float*)d_in[7];  const float* bv  = (const float*)d_in[8];
    const float* wo  = (const float*)d_in[9];  const float* bo  = (const float*)d_in[10];
    const float* wl  = (const float*)d_in[11]; const float* bl  = (const float*)d_in[12];
    const float* wr  = (const float*)d_in[13]; const float* br  = (const float*)d_in[14];
    const float* wrk = (const float*)d_in[15]; /* brk unused: softmax-invariant */
    const float* wrv = (const float*)d_in[17]; const float* brv = (const float*)d_in[18];

    float* out  = (float*)d_out;
    float* fout = out;                          // [B,N,D]
    float* ng   = out + (size_t)BB * NN * DD;   // [B,N,N,D]

    // Scratch in the tail of the ng region: all consumed before kE overwrites.
    const size_t ng_f  = (size_t)BB * NN * NN * DD;   // 67,108,864
    const size_t row_f = (size_t)BB * NN * DD;        // 262,144
    const size_t total = row_f * 52 + 32768;
    float* base = ng + ng_f - total;
    float* q    = base;
    float* k    = q   + row_f;
    float* vv_  = k   + row_f;
    float* qkp  = vv_ + row_f;          // row_f * 8
    float* skp  = qkp + row_f * 8;      // row_f * 4
    float* pg   = skp + row_f * 4;      // row_f * 32
    float* pxv  = pg  + row_f * 32;     // row_f * 4
    float* pm   = pxv + row_f * 4;      // 16384
    float* pl   = pm  + 16384;          // 16384
    float* om   = pl  + 16384;          // row_f
    float* xl = (float*)d_ws;           // survives into kE -> d_ws
    float* xr = xl + row_f;

    kProj<<<768, 256, 0, stream>>>(x, wq, bq, wk, bk, wv, bv, q, k, vv_);
    kQkp <<<2048, 256, 0, stream>>>(q, wrk, qkp);
    kSk  <<<2048, 256, 0, stream>>>(q, k, mask, skp);
    kC   <<<2048, 256, 0, stream>>>(G, skp, qkp, vv_, pg, pxv, pm, pl);
    kM   <<<1024, 256, 0, stream>>>(pg, pxv, pm, pl, wrv, brv, om);
    kProj<<<768, 256, 0, stream>>>(om, wo, bo, wl, bl, wr, br, fout, xl, xr);
    kE   <<<2048, 256, 0, stream>>>(xl, xr, ng);
}

// Round 6
// 296.958 us; speedup vs baseline: 2.0837x; 1.0157x over previous
//
#include <hip/hip_runtime.h>

#define BB 2
#define NN 256
#define DD 512
#define HH 8

typedef float f4raw __attribute__((ext_vector_type(4)));

__device__ __forceinline__ float dot4(float4 a, float4 b) {
    return a.x*b.x + a.y*b.y + a.z*b.z + a.w*b.w;
}

__device__ __forceinline__ float4 f4fma(float s, float4 a, float4 acc) {
    acc.x += s * a.x; acc.y += s * a.y; acc.z += s * a.z; acc.w += s * a.w;
    return acc;
}

__device__ __forceinline__ void gload_lds16(const void* g, void* l) {
    __builtin_amdgcn_global_load_lds(
        (const __attribute__((address_space(1))) unsigned int*)g,
        (__attribute__((address_space(3))) unsigned int*)l, 16, 0, 0);
}

// Stage 8 rows x 512 floats (16KB) global->LDS with per-row XOR swizzle.
// LDS slot (y,c) receives source element (y,c^y): dest linear, source
// per-lane pre-swizzled (m173 pattern).
__device__ __forceinline__ void stage_swz(const char* rowbase, float4* dst, int w, int lane) {
    #pragma unroll
    for (int j = 0; j < 4; ++j) {
        const int f0 = w * 256 + j * 64;
        const int y = f0 >> 7;
        const int c = (f0 & 127) + lane;
        gload_lds16(rowbase + (size_t)y * 2048 + ((size_t)(c ^ y) << 4), &dst[f0]);
    }
}

// ---------------- kProj: 3 linear layers as tiled GEMM --------------------
// O = X @ W^T + b. grid 768 = 3 proj x 16 rowtiles x 16 coltiles (32x32 tile)
// block 256; K-chunk 64, double-buffered LDS, 2x2 micro-tile.
__global__ __launch_bounds__(256) void kProj(
    const float* __restrict__ in_,
    const float* __restrict__ w0, const float* __restrict__ b0,
    const float* __restrict__ w1, const float* __restrict__ b1,
    const float* __restrict__ w2, const float* __restrict__ b2,
    float* __restrict__ o0, float* __restrict__ o1, float* __restrict__ o2)
{
    __shared__ float4 xs[2][32 * 17];   // 32 rows x 16 float4 (+1 pad)
    __shared__ float4 ws[2][32 * 17];

    const int t = threadIdx.x;
    const int blk = blockIdx.x;
    const int proj = blk >> 8;
    const int rem = blk & 255;
    const int row0 = (rem >> 4) * 32;
    const int col0 = (rem & 15) * 32;

    const float* W; const float* Bp; float* O;
    if (proj == 0)      { W = w0; Bp = b0; O = o0; }
    else if (proj == 1) { W = w1; Bp = b1; O = o1; }
    else                { W = w2; Bp = b2; O = o2; }

    const int sr0 = t >> 4,          se0 = t & 15;
    const int sr1 = (t + 256) >> 4,  se1 = t & 15;
    const float4* X4 = (const float4*)in_;
    const float4* W4 = (const float4*)W;

    float4 rx0 = X4[(size_t)(row0 + sr0) * 128 + se0];
    float4 rx1 = X4[(size_t)(row0 + sr1) * 128 + se1];
    float4 rw0 = W4[(size_t)(col0 + sr0) * 128 + se0];
    float4 rw1 = W4[(size_t)(col0 + sr1) * 128 + se1];
    xs[0][sr0 * 17 + se0] = rx0;
    xs[0][sr1 * 17 + se1] = rx1;
    ws[0][sr0 * 17 + se0] = rw0;
    ws[0][sr1 * 17 + se1] = rw1;

    const int ty = t >> 4, tx = t & 15;
    const int ra = 2 * ty, ca = 2 * tx;
    float a00 = 0, a01 = 0, a10 = 0, a11 = 0;

    for (int q = 0; q < 8; ++q) {
        __syncthreads();
        const int cur = q & 1;
        if (q < 7) {
            const int koff = (q + 1) * 16;
            rx0 = X4[(size_t)(row0 + sr0) * 128 + koff + se0];
            rx1 = X4[(size_t)(row0 + sr1) * 128 + koff + se1];
            rw0 = W4[(size_t)(col0 + sr0) * 128 + koff + se0];
            rw1 = W4[(size_t)(col0 + sr1) * 128 + koff + se1];
        }
        const float4* xb = xs[cur];
        const float4* wb = ws[cur];
        #pragma unroll
        for (int e4 = 0; e4 < 16; ++e4) {
            const float4 x0 = xb[ra * 17 + e4];
            const float4 x1 = xb[(ra + 1) * 17 + e4];
            const float4 v0 = wb[ca * 17 + e4];
            const float4 v1 = wb[(ca + 1) * 17 + e4];
            a00 += dot4(x0, v0); a01 += dot4(x0, v1);
            a10 += dot4(x1, v0); a11 += dot4(x1, v1);
        }
        if (q < 7) {
            const int nxt = cur ^ 1;
            xs[nxt][sr0 * 17 + se0] = rx0;
            xs[nxt][sr1 * 17 + se1] = rx1;
            ws[nxt][sr0 * 17 + se0] = rw0;
            ws[nxt][sr1 * 17 + se1] = rw1;
        }
    }

    const int orow = row0 + ra, ocol = col0 + ca;
    const float bx = Bp[ocol], by = Bp[ocol + 1];
    float2 s0; s0.x = a00 + bx; s0.y = a01 + by;
    float2 s1; s1.x = a10 + bx; s1.y = a11 + by;
    *(float2*)(O + (size_t)orow * DD + ocol) = s0;
    *(float2*)(O + (size_t)(orow + 1) * DD + ocol) = s1;
}

// ---------------- kQkp: qkp[row,h,e] = sum_d q[row,h*64+d]*wrk[h*64+d,e] ----
// grid 2048 = 64 rowgroups(8 rows) x 8 h x 4 e-slices(128); block 256
__global__ __launch_bounds__(256) void kQkp(
    const float* __restrict__ q, const float* __restrict__ wrk,
    float* __restrict__ qkp)
{
    __shared__ float qs[8 * 64];
    const int t = threadIdx.x;
    const int blk = blockIdx.x;
    const int rowg = blk >> 5;
    const int h = (blk >> 2) & 7;
    const int eq = blk & 3;
    const int row0 = rowg * 8;
    {
        const int r = t >> 5, d2 = (t & 31) * 2;
        const float2 tmp = *(const float2*)(q + (size_t)(row0 + r) * DD + h * 64 + d2);
        qs[r * 64 + d2] = tmp.x; qs[r * 64 + d2 + 1] = tmp.y;
    }
    __syncthreads();
    const int e = eq * 128 + (t & 127);
    const int rp = (t >> 7) * 4;
    const float* wcol = wrk + (size_t)(h * 64) * DD + e;
    float a0 = 0, a1 = 0, a2 = 0, a3 = 0;
    #pragma unroll 8
    for (int d = 0; d < 64; ++d) {
        const float wv = wcol[(size_t)d * DD];
        a0 += qs[(rp + 0) * 64 + d] * wv;
        a1 += qs[(rp + 1) * 64 + d] * wv;
        a2 += qs[(rp + 2) * 64 + d] * wv;
        a3 += qs[(rp + 3) * 64 + d] * wv;
    }
    qkp[((size_t)(row0 + rp + 0) * HH + h) * DD + e] = a0;
    qkp[((size_t)(row0 + rp + 1) * HH + h) * DD + e] = a1;
    qkp[((size_t)(row0 + rp + 2) * HH + h) * DD + e] = a2;
    qkp[((size_t)(row0 + rp + 3) * HH + h) * DD + e] = a3;
}

// ---------------- kSk: sk[b,x,h,y] = 0.125*(q.k) + mask ----------------
// grid 2048 = 2b x 8h x 32 xt(8 rows) x 4 yt(64); block 256
__global__ __launch_bounds__(256) void kSk(
    const float* __restrict__ q, const float* __restrict__ k,
    const unsigned char* __restrict__ mask, float* __restrict__ sk)
{
    __shared__ float qs[8 * 65];
    __shared__ float ks[64 * 65];
    const int t = threadIdx.x;
    const int blk = blockIdx.x;
    const int b  = blk >> 10;
    const int h  = (blk >> 7) & 7;
    const int xt = (blk >> 2) & 31;
    const int yt = blk & 3;
    const int x0 = xt * 8, y0 = yt * 64;
    {
        const int r = t >> 5, d2 = (t & 31) * 2;
        const float2 tmp = *(const float2*)(q + (size_t)(b * NN + x0 + r) * DD + h * 64 + d2);
        qs[r * 65 + d2] = tmp.x; qs[r * 65 + d2 + 1] = tmp.y;
    }
    #pragma unroll
    for (int j = 0; j < 8; ++j) {
        const int f = t + 256 * j;
        const int r = f >> 5, d2 = (f & 31) * 2;
        const float2 tmp = *(const float2*)(k + (size_t)(b * NN + y0 + r) * DD + h * 64 + d2);
        ks[r * 65 + d2] = tmp.x; ks[r * 65 + d2 + 1] = tmp.y;
    }
    __syncthreads();
    const int xi = t >> 5, yg = t & 31;
    float a0 = 0, a1 = 0;
    #pragma unroll 8
    for (int d = 0; d < 64; ++d) {
        const float qv = qs[xi * 65 + d];
        a0 += qv * ks[(yg * 2 + 0) * 65 + d];
        a1 += qv * ks[(yg * 2 + 1) * 65 + d];
    }
    a0 *= 0.125f; a1 *= 0.125f;
    const unsigned char* mrow = mask + (size_t)(b * NN + x0 + xi) * NN;
    const int gy = y0 + yg * 2;
    if (mrow[gy + 0]) a0 = -1e9f;
    if (mrow[gy + 1]) a1 = -1e9f;
    float2 st; st.x = a0; st.y = a1;
    *(float2*)(sk + ((size_t)(b * NN + x0 + xi) * HH + h) * NN + gy) = st;
}

// ---------------- kC: flash attention over G, split-K 4 parts -------------
// grid 2048 = (b*N) x 4 parts; block 256; each block handles 64 y rows.
// qkp fragments and the 8x8 score tile live in REGISTERS; LDS holds only
// the double-buffered G tile + the 64-float score exchange buffer.
__global__ __launch_bounds__(256) void kC(
    const float* __restrict__ G, const float* __restrict__ sk,
    const float* __restrict__ qkp, const float* __restrict__ v,
    float* __restrict__ pg, float* __restrict__ pxv,
    float* __restrict__ pm, float* __restrict__ pl)
{
    __shared__ float4 gbuf[2][1024];   // double-buffered 8x512 G tile, swizzled
    __shared__ float s_l[64];          // scores [8y][8h]

    const int t = threadIdx.x;
    const int lane = t & 63;
    const int w = t >> 6;
    const int blk = blockIdx.x;
    const int part = blk & 3;
    const int bid = blk >> 2;          // b*N + x
    const int b = bid >> 8;
    const int ybase = part * 64;

    const char* Grow = (const char*)(G + (size_t)bid * NN * DD);
    stage_swz(Grow + (size_t)ybase * 2048, &gbuf[0][0], w, lane);

    const int s_  = t & 15;
    const int h0i = ((t >> 4) & 3) * 2;
    const int y0i = w * 2;
    const int ec4 = t & 127;
    const int hb  = (t >> 7) * 4;
    const int hv  = t >> 5;
    const int d2  = (t & 31) * 2;
    const int ri  = hv & 3;            // which of p0..p3 is this thread's x_v head

    // qkp fragments for this thread's two h-rows, all 8 e-slices, in regs
    const float* qkpb = qkp + (size_t)bid * HH * DD;
    float4 qv0[8], qv1[8];
    #pragma unroll
    for (int i = 0; i < 8; ++i) {
        const int e4 = i * 16 + s_;
        qv0[i] = *(const float4*)(qkpb + (size_t)h0i * DD + e4 * 4);
        qv1[i] = *(const float4*)(qkpb + (size_t)(h0i + 1) * DD + e4 * 4);
    }

    float4 gacc0 = {0,0,0,0}, gacc1 = {0,0,0,0}, gacc2 = {0,0,0,0}, gacc3 = {0,0,0,0};
    float m0 = -3e38f, m1 = -3e38f, m2 = -3e38f, m3 = -3e38f;
    float l0 = 0, l1 = 0, l2 = 0, l3 = 0;
    float vx = 0, vy = 0;

    const float* vrow = v + (size_t)(b * NN + ybase) * DD + hv * 64 + d2;
    const float* skrow = sk + (size_t)bid * HH * NN;

    __syncthreads();   // gbuf[0] staged (vmcnt drained by barrier)

    int cb = 0;
    for (int tt = 0; tt < 8; ++tt) {
        if (tt < 7)
            stage_swz(Grow + (size_t)(ybase + (tt + 1) * 8) * 2048, &gbuf[cb ^ 1][0], w, lane);

        // hoist v loads: latency hides under score phase
        float2 vvs[8];
        #pragma unroll
        for (int y = 0; y < 8; ++y)
            vvs[y] = *(const float2*)(vrow + ((size_t)tt * 8 + y) * DD);

        // ---- scores (2y x 2h per 16-lane slice, qkp from regs) ----
        {
            float a00 = 0, a01 = 0, a10 = 0, a11 = 0;
            const float4* gb = &gbuf[cb][0];
            #pragma unroll
            for (int i = 0; i < 8; ++i) {
                const int e4 = i * 16 + s_;
                const float4 g0 = gb[y0i * 128 + (e4 ^ y0i)];
                const float4 g1 = gb[(y0i + 1) * 128 + (e4 ^ (y0i + 1))];
                a00 += dot4(g0, qv0[i]); a01 += dot4(g0, qv1[i]);
                a10 += dot4(g1, qv0[i]); a11 += dot4(g1, qv1[i]);
            }
            #pragma unroll
            for (int mm = 1; mm < 16; mm <<= 1) {
                a00 += __shfl_xor(a00, mm); a01 += __shfl_xor(a01, mm);
                a10 += __shfl_xor(a10, mm); a11 += __shfl_xor(a11, mm);
            }
            if (s_ < 4) {
                const int yy = s_ & 1, hh = s_ >> 1;
                const float val = yy ? (hh ? a11 : a10) : (hh ? a01 : a00);
                const int gy = ybase + tt * 8 + y0i + yy;
                const int h = h0i + hh;
                s_l[(y0i + yy) * 8 + h] = val * 0.125f + skrow[(size_t)h * NN + gy];
            }
        }
        __syncthreads();

        // ---- s tile -> regs (wave-uniform float4 reads) ----
        float4 sv[8];
        #pragma unroll
        for (int y = 0; y < 8; ++y) sv[y] = *(const float4*)&s_l[y * 8 + hb];

        // ---- softmax update from regs ----
        float4 mx = sv[0];
        #pragma unroll
        for (int y = 1; y < 8; ++y) {
            mx.x = fmaxf(mx.x, sv[y].x); mx.y = fmaxf(mx.y, sv[y].y);
            mx.z = fmaxf(mx.z, sv[y].z); mx.w = fmaxf(mx.w, sv[y].w);
        }
        const float n0 = fmaxf(m0, mx.x), rs0 = __expf(m0 - n0);
        const float n1 = fmaxf(m1, mx.y), rs1 = __expf(m1 - n1);
        const float n2 = fmaxf(m2, mx.z), rs2 = __expf(m2 - n2);
        const float n3 = fmaxf(m3, mx.w), rs3 = __expf(m3 - n3);
        m0 = n0; m1 = n1; m2 = n2; m3 = n3;
        l0 *= rs0; l1 *= rs1; l2 *= rs2; l3 *= rs3;
        gacc0.x *= rs0; gacc0.y *= rs0; gacc0.z *= rs0; gacc0.w *= rs0;
        gacc1.x *= rs1; gacc1.y *= rs1; gacc1.z *= rs1; gacc1.w *= rs1;
        gacc2.x *= rs2; gacc2.y *= rs2; gacc2.z *= rs2; gacc2.w *= rs2;
        gacc3.x *= rs3; gacc3.y *= rs3; gacc3.z *= rs3; gacc3.w *= rs3;
        const float rsv = (ri == 0) ? rs0 : (ri == 1) ? rs1 : (ri == 2) ? rs2 : rs3;
        vx *= rsv; vy *= rsv;

        // ---- accumulate ----
        {
            const float4* gb = &gbuf[cb][0];
            #pragma unroll
            for (int y = 0; y < 8; ++y) {
                const float4 gv = gb[y * 128 + (ec4 ^ y)];
                const float4 s = sv[y];
                const float p0 = __expf(s.x - m0); l0 += p0; gacc0 = f4fma(p0, gv, gacc0);
                const float p1 = __expf(s.y - m1); l1 += p1; gacc1 = f4fma(p1, gv, gacc1);
                const float p2 = __expf(s.z - m2); l2 += p2; gacc2 = f4fma(p2, gv, gacc2);
                const float p3 = __expf(s.w - m3); l3 += p3; gacc3 = f4fma(p3, gv, gacc3);
                const float pv = (ri == 0) ? p0 : (ri == 1) ? p1 : (ri == 2) ? p2 : p3;
                vx += pv * vvs[y].x; vy += pv * vvs[y].y;
            }
        }
        __syncthreads();
        cb ^= 1;
    }

    float4* pgb = (float4*)pg + (size_t)blk * 1024;
    pgb[(hb + 0) * 128 + ec4] = gacc0;
    pgb[(hb + 1) * 128 + ec4] = gacc1;
    pgb[(hb + 2) * 128 + ec4] = gacc2;
    pgb[(hb + 3) * 128 + ec4] = gacc3;
    float2 xvst; xvst.x = vx; xvst.y = vy;
    *(float2*)(pxv + (size_t)blk * DD + hv * 64 + d2) = xvst;
    if ((t & 127) == 0) {
        const int base = blk * 8 + hb;
        pm[base + 0] = m0; pm[base + 1] = m1; pm[base + 2] = m2; pm[base + 3] = m3;
        pl[base + 0] = l0; pl[base + 1] = l1; pl[base + 2] = l2; pl[base + 3] = l3;
    }
}

// ---------------- kM: merge 4 partials + wrv GEMV epilogue ----------------
// grid 1024 = bid x 2 output-halves (h 0-3 / 4-7); block 256
__global__ __launch_bounds__(256) void kM(
    const float* __restrict__ pg, const float* __restrict__ pxv,
    const float* __restrict__ pm, const float* __restrict__ pl,
    const float* __restrict__ wrv, const float* __restrict__ brv,
    float* __restrict__ om)
{
    __shared__ float4 gc[512];      // combined g_agg [4h][128]
    __shared__ float xvs[256];
    __shared__ float wexp[16], Ls[4];
    const int t = threadIdx.x;
    const int blk = blockIdx.x;
    const int bid = blk >> 1;
    const int half = blk & 1;
    const int h0 = half * 4;
    __shared__ float mlds[16], llds[16];
    if (t < 16) {
        const int i = t >> 2, hh = t & 3;
        mlds[t] = pm[bid * 32 + i * 8 + h0 + hh];
        llds[t] = pl[bid * 32 + i * 8 + h0 + hh];
    }
    __syncthreads();
    if (t < 4) {
        float M = mlds[t];
        #pragma unroll
        for (int i = 1; i < 4; ++i) M = fmaxf(M, mlds[i * 4 + t]);
        float L = 0;
        #pragma unroll
        for (int i = 0; i < 4; ++i) {
            const float wv = __expf(mlds[i * 4 + t] - M);
            wexp[i * 4 + t] = wv;
            L += wv * llds[i * 4 + t];
        }
        Ls[t] = L;
    }
    __syncthreads();
    const int c4 = t & 127;
    #pragma unroll
    for (int r = 0; r < 2; ++r) {
        const int hh = (t >> 7) * 2 + r;       // 0..3 local
        float4 acc = {0, 0, 0, 0};
        #pragma unroll
        for (int i = 0; i < 4; ++i) {
            const float wv = wexp[i * 4 + hh];
            const float4 g = ((const float4*)pg)[((size_t)bid * 4 + i) * 1024 + (size_t)(h0 + hh) * 128 + c4];
            acc.x += wv * g.x; acc.y += wv * g.y; acc.z += wv * g.z; acc.w += wv * g.w;
        }
        gc[hh * 128 + c4] = acc;
    }
    {
        const int hh = t >> 6;                 // 0..3 local
        float s = 0;
        #pragma unroll
        for (int i = 0; i < 4; ++i)
            s += wexp[i * 4 + hh] * pxv[((size_t)bid * 4 + i) * DD + half * 256 + t];
        xvs[t] = s;
    }
    __syncthreads();
    const int o = half * 256 + t;
    const int hl = t >> 6;                     // 0..3 local
    const float4* wr4 = (const float4*)(wrv + (size_t)o * DD);
    float acc = 0;
    #pragma unroll 4
    for (int e4 = 0; e4 < 128; ++e4) acc += dot4(wr4[e4], gc[hl * 128 + e4]);
    om[(size_t)bid * DD + o] = (xvs[t] + acc) / Ls[hl] + brv[o];
}

// ---------------- kE: new_graphs = xl[:,:,None,:] + xr[:,None,:,:] -------
// grid 2048 = 512 bid x 4 y-chunks; block 256; nontemporal streaming stores
__global__ __launch_bounds__(256) void kE(
    const float* __restrict__ xl, const float* __restrict__ xr,
    float* __restrict__ ng)
{
    const int t = threadIdx.x;
    const int blk = blockIdx.x;
    const int bid = blk >> 2;
    const int yc = blk & 3;
    const int b = bid >> 8;
    const int o4 = t & 127;
    const int yh = t >> 7;
    const float4 left = ((const float4*)xl)[(size_t)bid * 128 + o4];
    const float4* xr4 = (const float4*)xr + (size_t)b * NN * 128;
    f4raw* out4 = (f4raw*)ng + (size_t)bid * NN * 128;
    for (int y = yc * 64 + yh; y < yc * 64 + 64; y += 2) {
        const float4 rr = xr4[y * 128 + o4];
        f4raw s;
        s.x = left.x + rr.x; s.y = left.y + rr.y;
        s.z = left.z + rr.z; s.w = left.w + rr.w;
        __builtin_nontemporal_store(s, &out4[y * 128 + o4]);
    }
}

extern "C" void kernel_launch(void* const* d_in, const int* in_sizes, int n_in,
                              void* d_out, int out_size, void* d_ws, size_t ws_size,
                              hipStream_t stream)
{
    (void)in_sizes; (void)n_in; (void)out_size; (void)ws_size;
    const float* x    = (const float*)d_in[0];
    const float* G    = (const float*)d_in[1];
    const unsigned char* mask = (const unsigned char*)d_in[2];
    const float* wq  = (const float*)d_in[3];  const float* bq  = (const float*)d_in[4];
    const float* wk  = (const float*)d_in[5];  const float* bk  = (const float*)d_in[6];
    const float* wv  = (const float*)d_in[7];  const float* bv  = (const float*)d_in[8];
    const float* wo  = (const float*)d_in[9];  const float* bo  = (const float*)d_in[10];
    const float* wl  = (const float*)d_in[11]; const float* bl  = (const float*)d_in[12];
    const float* wr  = (const float*)d_in[13]; const float* br  = (const float*)d_in[14];
    const float* wrk = (const float*)d_in[15]; /* brk unused: softmax-invariant */
    const float* wrv = (const float*)d_in[17]; const float* brv = (const float*)d_in[18];

    float* out  = (float*)d_out;
    float* fout = out;                          // [B,N,D]
    float* ng   = out + (size_t)BB * NN * DD;   // [B,N,N,D]

    // Scratch in the tail of the ng region: all consumed before kE overwrites.
    const size_t ng_f  = (size_t)BB * NN * NN * DD;   // 67,108,864
    const size_t row_f = (size_t)BB * NN * DD;        // 262,144
    const size_t total = row_f * 52 + 32768;
    float* base = ng + ng_f - total;
    float* q    = base;
    float* k    = q   + row_f;
    float* vv_  = k   + row_f;
    float* qkp  = vv_ + row_f;          // row_f * 8
    float* skp  = qkp + row_f * 8;      // row_f * 4
    float* pg   = skp + row_f * 4;      // row_f * 32
    float* pxv  = pg  + row_f * 32;     // row_f * 4
    float* pm   = pxv + row_f * 4;      // 16384
    float* pl   = pm  + 16384;          // 16384
    float* om   = pl  + 16384;          // row_f
    float* xl = (float*)d_ws;           // survives into kE -> d_ws
    float* xr = xl + row_f;

    kProj<<<768, 256, 0, stream>>>(x, wq, bq, wk, bk, wv, bv, q, k, vv_);
    kQkp <<<2048, 256, 0, stream>>>(q, wrk, qkp);
    kSk  <<<2048, 256, 0, stream>>>(q, k, mask, skp);
    kC   <<<2048, 256, 0, stream>>>(G, skp, qkp, vv_, pg, pxv, pm, pl);
    kM   <<<1024, 256, 0, stream>>>(pg, pxv, pm, pl, wrv, brv, om);
    kProj<<<768, 256, 0, stream>>>(om, wo, bo, wl, bl, wr, br, fout, xl, xr);
    kE   <<<2048, 256, 0, stream>>>(xl, xr, ng);
}